// Round 8
// baseline (184.714 us; speedup 1.0000x reference)
//
#include <hip/hip_runtime.h>
#include <hip/hip_bf16.h>
#include <hip/hip_fp16.h>
#include <cstddef>

#define N_NODES 50000
#define IN_DIM 256
#define HID_DIM 64
#define OUT_DIM 40
#define N_EDGES 800000

typedef _Float16 f16x8 __attribute__((ext_vector_type(8)));
typedef float f32x4 __attribute__((ext_vector_type(4)));

static_assert(N_NODES % 4 == 0, "agg grid assumes 4 nodes per block");

// ---------------------------------------------------------------------------
// K0: zero histogram + build W1^T in fp16 (w1t[c][k] = W1[k][c])
__global__ void k_init(int* __restrict__ cnt, const float* __restrict__ W1,
                       __half* __restrict__ w1t) {
    int i = blockIdx.x * 256 + threadIdx.x;
    if (i < N_NODES) cnt[i] = 0;
    if (i < IN_DIM * HID_DIM) {
        int c = i >> 8, k = i & 255;
        w1t[i] = __float2half(W1[(size_t)k * HID_DIM + c]);
    }
}

// K1: degree histogram over dst; atomic return value = rank within dst bucket
__global__ void k_count(const int* __restrict__ dst, int* __restrict__ cnt,
                        unsigned short* __restrict__ rank_, int E) {
    int i = blockIdx.x * blockDim.x + threadIdx.x;
    if (i < E) rank_[i] = (unsigned short)atomicAdd(&cnt[dst[i]], 1);
}

// K2a: per-block exclusive scan of cnt -> rowptr (block-local) + block sums
__global__ void k_scan1(const int* __restrict__ cnt, int* __restrict__ excl,
                        int* __restrict__ bsum) {
    __shared__ int wsum[4];
    int i = blockIdx.x * 256 + threadIdx.x;
    int lane = threadIdx.x & 63, w = threadIdx.x >> 6;
    int v = (i < N_NODES) ? cnt[i] : 0;
    int inc = v;
    for (int o = 1; o < 64; o <<= 1) {
        int t = __shfl_up(inc, o);
        if (lane >= o) inc += t;
    }
    if (lane == 63) wsum[w] = inc;
    __syncthreads();
    int off = 0;
    for (int k = 0; k < w; ++k) off += wsum[k];
    if (i < N_NODES) excl[i] = off + inc - v;
    if (threadIdx.x == 255) bsum[blockIdx.x] = off + inc;
}

// K2b: single-block exclusive scan of the block sums (nb <= 256)
__global__ void k_scan2(int* __restrict__ bsum, int nb) {
    __shared__ int wsum[4];
    int i = threadIdx.x;
    int lane = i & 63, w = i >> 6;
    int v = (i < nb) ? bsum[i] : 0;
    int inc = v;
    for (int o = 1; o < 64; o <<= 1) {
        int t = __shfl_up(inc, o);
        if (lane >= o) inc += t;
    }
    if (lane == 63) wsum[w] = inc;
    __syncthreads();
    int off = 0;
    for (int k = 0; k < w; ++k) off += wsum[k];
    if (i < nb) bsum[i] = off + inc - v;
}

// K2c: add block offsets; append rowptr[N] = E; also dinv = rsqrt(deg+1)
__global__ void k_scan3_dinv(int* __restrict__ rowptr, const int* __restrict__ bsum,
                             const int* __restrict__ cnt, float* __restrict__ dinv) {
    int i = blockIdx.x * 256 + threadIdx.x;
    if (i < N_NODES) {
        rowptr[i] += bsum[blockIdx.x];
        dinv[i] = rsqrtf((float)cnt[i] + 1.0f);
    } else if (i == N_NODES) {
        rowptr[i] = N_EDGES;
    }
}

// K3: atomic-free bucket fill using precomputed rank (uint16 edge ids)
__global__ void k_fill(const int* __restrict__ src, const int* __restrict__ dst,
                       const int* __restrict__ rowptr,
                       const unsigned short* __restrict__ rank_,
                       unsigned short* __restrict__ esrc, int E) {
    int i = blockIdx.x * blockDim.x + threadIdx.x;
    if (i < E) {
        int d = dst[i];
        esrc[rowptr[d] + rank_[i]] = (unsigned short)src[i];
    }
}

// K4: g1 = dinv * (x @ W1) via fp16 MFMA (fp32 accumulate), fp16 output.
__global__ __launch_bounds__(256) void k_gemm1(const float* __restrict__ x,
        const __half* __restrict__ w1t, const float* __restrict__ dinv,
        __half* __restrict__ g1) {
    __shared__ _Float16 xh[64][264];
    __shared__ _Float16 wt[64][264];
    const int tid = threadIdx.x;
    const int row0 = blockIdx.x * 64;
    {
        int r = tid >> 2, q = tid & 3;
        const uint4* wsrc = (const uint4*)(w1t + (size_t)r * 256 + q * 64);
        uint4* wdst = (uint4*)&wt[r][q * 64];
#pragma unroll
        for (int i = 0; i < 8; ++i) wdst[i] = wsrc[i];
        int grow = row0 + r;
        const float4* xsrc = (const float4*)(x + (size_t)grow * IN_DIM + q * 64);
#pragma unroll
        for (int i = 0; i < 8; ++i) {
            float4 f0 = make_float4(0.f, 0.f, 0.f, 0.f), f1 = f0;
            if (grow < N_NODES) { f0 = xsrc[2 * i]; f1 = xsrc[2 * i + 1]; }
            f16x8 v;
            v[0] = (_Float16)f0.x; v[1] = (_Float16)f0.y;
            v[2] = (_Float16)f0.z; v[3] = (_Float16)f0.w;
            v[4] = (_Float16)f1.x; v[5] = (_Float16)f1.y;
            v[6] = (_Float16)f1.z; v[7] = (_Float16)f1.w;
            *(f16x8*)&xh[r][q * 64 + i * 8] = v;
        }
    }
    __syncthreads();
    const int wv = tid >> 6, l = tid & 63;
    const int rowa = wv * 16 + (l & 15);
    const int koff = (l >> 4) * 8;
    f32x4 acc0 = {0.f, 0.f, 0.f, 0.f}, acc1 = acc0, acc2 = acc0, acc3 = acc0;
#pragma unroll
    for (int ks = 0; ks < 8; ++ks) {
        f16x8 a  = *(const f16x8*)&xh[rowa][ks * 32 + koff];
        f16x8 b0 = *(const f16x8*)&wt[ 0 + (l & 15)][ks * 32 + koff];
        f16x8 b1 = *(const f16x8*)&wt[16 + (l & 15)][ks * 32 + koff];
        f16x8 b2 = *(const f16x8*)&wt[32 + (l & 15)][ks * 32 + koff];
        f16x8 b3 = *(const f16x8*)&wt[48 + (l & 15)][ks * 32 + koff];
        acc0 = __builtin_amdgcn_mfma_f32_16x16x32_f16(a, b0, acc0, 0, 0, 0);
        acc1 = __builtin_amdgcn_mfma_f32_16x16x32_f16(a, b1, acc1, 0, 0, 0);
        acc2 = __builtin_amdgcn_mfma_f32_16x16x32_f16(a, b2, acc2, 0, 0, 0);
        acc3 = __builtin_amdgcn_mfma_f32_16x16x32_f16(a, b3, acc3, 0, 0, 0);
    }
    // C/D: col = lane&15, row = (lane>>4)*4 + reg  [m89-verified]
    const int colc = l & 15;
#pragma unroll
    for (int r = 0; r < 4; ++r) {
        int grow = row0 + wv * 16 + (l >> 4) * 4 + r;
        if (grow < N_NODES) {
            float dv = dinv[grow];
            __half* dst = g1 + (size_t)grow * HID_DIM;
            dst[ 0 + colc] = __float2half(acc0[r] * dv);
            dst[16 + colc] = __float2half(acc1[r] * dv);
            dst[32 + colc] = __float2half(acc2[r] * dv);
            dst[48 + colc] = __float2half(acc3[r] * dv);
        }
    }
}

// K5: FUSED layer-1 aggregation + bias + ReLU + (h @ W2) + dinv prescale.
// One wave per node (grid exactly N_NODES/4 blocks). Gathers pre-scaled g1
// rows; after the parity reduce EVERY lane holds h for its channel group
// (c = lane&15); the W2 dot uses 16 readlane-broadcasts x 4 FMAs per output
// column; lane c<40 writes g2[wid][c] = dinv[wid] * (h @ W2)[c] in fp16.
__global__ __launch_bounds__(256) void k_agg1(const int* __restrict__ rowptr,
        const unsigned short* __restrict__ esrc, const float* __restrict__ dinv,
        const uint2* __restrict__ g,        // [N][16] uint2 (=64 half)
        const float* __restrict__ b,        // b1[64]
        const float* __restrict__ W2,       // [64][40] row-major
        __half* __restrict__ g2) {          // [N][40] fp16
    __shared__ float w2s[HID_DIM * OUT_DIM];   // [k][c], 10.24 KB
    for (int i = threadIdx.x; i < HID_DIM * OUT_DIM; i += 256) w2s[i] = W2[i];
    __syncthreads();

    int wid  = (int)((blockIdx.x * (size_t)blockDim.x + threadIdx.x) >> 6);
    int lane = threadIdx.x & 63;
    int p = lane >> 4;        // edge parity 0..3
    int c = lane & 15;        // uint2 channel group
    float ax = 0.f, ay = 0.f, az = 0.f, aw = 0.f;
#define ACC_U2(v)  do {                                            \
        float2 f0 = __half22float2(*(const __half2*)&(v).x);       \
        float2 f1 = __half22float2(*(const __half2*)&(v).y);       \
        ax += f0.x; ay += f0.y; az += f1.x; aw += f1.y; } while (0)
    if (p == 0) { uint2 v = g[(size_t)wid * 16 + c]; ACC_U2(v); }  // self-loop
    int beg = rowptr[wid], end = rowptr[wid + 1];
    int j = beg + p;
    for (; j + 12 < end; j += 16) {
        int s0 = esrc[j], s1 = esrc[j + 4], s2 = esrc[j + 8], s3 = esrc[j + 12];
        uint2 v0 = g[(size_t)s0 * 16 + c];
        uint2 v1 = g[(size_t)s1 * 16 + c];
        uint2 v2 = g[(size_t)s2 * 16 + c];
        uint2 v3 = g[(size_t)s3 * 16 + c];
        ACC_U2(v0); ACC_U2(v1); ACC_U2(v2); ACC_U2(v3);
    }
    for (; j < end; j += 4) { uint2 v = g[(size_t)esrc[j] * 16 + c]; ACC_U2(v); }
#undef ACC_U2
    // butterfly over lane bits 4,5: every lane now holds the full sum for c
    ax += __shfl_xor(ax, 16); ax += __shfl_xor(ax, 32);
    ay += __shfl_xor(ay, 16); ay += __shfl_xor(ay, 32);
    az += __shfl_xor(az, 16); az += __shfl_xor(az, 32);
    aw += __shfl_xor(aw, 16); aw += __shfl_xor(aw, 32);
    float dd = dinv[wid];
    float4 bb = *(const float4*)&b[c * 4];
    float hx = fmaxf(ax * dd + bb.x, 0.f);
    float hy = fmaxf(ay * dd + bb.y, 0.f);
    float hz = fmaxf(az * dd + bb.z, 0.f);
    float hw = fmaxf(aw * dd + bb.w, 0.f);
    // W2 dot: lane cc computes output column cc (cc<40)
    int cc = (lane < OUT_DIM) ? lane : 0;
    float o = 0.f;
#pragma unroll
    for (int l = 0; l < 16; ++l) {
        float h0 = __shfl(hx, l);
        float h1 = __shfl(hy, l);
        float h2 = __shfl(hz, l);
        float h3 = __shfl(hw, l);
        o += h0 * w2s[(l * 4 + 0) * OUT_DIM + cc];
        o += h1 * w2s[(l * 4 + 1) * OUT_DIM + cc];
        o += h2 * w2s[(l * 4 + 2) * OUT_DIM + cc];
        o += h3 * w2s[(l * 4 + 3) * OUT_DIM + cc];
    }
    if (lane < OUT_DIM)
        g2[(size_t)wid * OUT_DIM + lane] = __float2half(o * dd);
}

// K6: layer-2 aggregation (pre-scaled fp16 in), fused bias + log_softmax.
__global__ __launch_bounds__(256) void k_agg_lsm(const int* __restrict__ rowptr,
        const unsigned short* __restrict__ esrc, const float* __restrict__ dinv,
        const uint2* __restrict__ g,        // [N][10] uint2 (=40 half)
        const float* __restrict__ b,
        float* __restrict__ out) {
    int wid  = (int)((blockIdx.x * (size_t)blockDim.x + threadIdx.x) >> 6);
    int lane = threadIdx.x & 63;
    if (wid >= N_NODES) return;
    int p = lane >> 4;
    int c = lane & 15;
    bool act = (c < 10);
    float ax = 0.f, ay = 0.f, az = 0.f, aw = 0.f;
#define ACC_U2(v)  do {                                            \
        float2 f0 = __half22float2(*(const __half2*)&(v).x);       \
        float2 f1 = __half22float2(*(const __half2*)&(v).y);       \
        ax += f0.x; ay += f0.y; az += f1.x; aw += f1.y; } while (0)
    if (p == 0 && act) { uint2 v = g[(size_t)wid * 10 + c]; ACC_U2(v); }
    int beg = rowptr[wid], end = rowptr[wid + 1];
    int j = beg + p;
    if (act) {
        for (; j + 12 < end; j += 16) {
            int s0 = esrc[j], s1 = esrc[j + 4], s2 = esrc[j + 8], s3 = esrc[j + 12];
            uint2 v0 = g[(size_t)s0 * 10 + c];
            uint2 v1 = g[(size_t)s1 * 10 + c];
            uint2 v2 = g[(size_t)s2 * 10 + c];
            uint2 v3 = g[(size_t)s3 * 10 + c];
            ACC_U2(v0); ACC_U2(v1); ACC_U2(v2); ACC_U2(v3);
        }
        for (; j < end; j += 4) { uint2 v = g[(size_t)esrc[j] * 10 + c]; ACC_U2(v); }
    }
#undef ACC_U2
    ax += __shfl_xor(ax, 16); ax += __shfl_xor(ax, 32);
    ay += __shfl_xor(ay, 16); ay += __shfl_xor(ay, 32);
    az += __shfl_xor(az, 16); az += __shfl_xor(az, 32);
    aw += __shfl_xor(aw, 16); aw += __shfl_xor(aw, 32);
    float dd = dinv[wid];
    float vx = -INFINITY, vy = -INFINITY, vz = -INFINITY, vw = -INFINITY;
    if (act) {
        float4 bb = *(const float4*)&b[c * 4];
        vx = ax * dd + bb.x; vy = ay * dd + bb.y;
        vz = az * dd + bb.z; vw = aw * dd + bb.w;
    }
    float m = fmaxf(fmaxf(vx, vy), fmaxf(vz, vw));
    for (int o = 8; o; o >>= 1) m = fmaxf(m, __shfl_xor(m, o));
    float es = act ? (__expf(vx - m) + __expf(vy - m) + __expf(vz - m) + __expf(vw - m)) : 0.f;
    for (int o = 8; o; o >>= 1) es += __shfl_xor(es, o);
    float ls = __logf(es);
    if (lane < 16 && act) {
        float4 o4 = make_float4(vx - m - ls, vy - m - ls, vz - m - ls, vw - m - ls);
        *(float4*)&out[(size_t)wid * OUT_DIM + c * 4] = o4;
    }
}

extern "C" void kernel_launch(void* const* d_in, const int* in_sizes, int n_in,
                              void* d_out, int out_size, void* d_ws, size_t ws_size,
                              hipStream_t stream) {
    const float* x    = (const float*)d_in[0];
    const int*   ei   = (const int*)d_in[1];
    const int*   srcp = ei;             // edge_index[0]
    const int*   dstp = ei + N_EDGES;   // edge_index[1]
    const float* W1   = (const float*)d_in[2];
    const float* b1   = (const float*)d_in[3];
    const float* W2   = (const float*)d_in[4];
    const float* b2   = (const float*)d_in[5];
    float* out = (float*)d_out;

    // workspace layout (~14.5 MB), all offsets >=4B aligned
    char* p = (char*)d_ws;
    int*            cnt    = (int*)p;            p += (size_t)N_NODES * 4;
    int*            rowptr = (int*)p;            p += (size_t)(N_NODES + 4) * 4;
    unsigned short* rank_  = (unsigned short*)p; p += (size_t)N_EDGES * 2;
    unsigned short* esrc   = (unsigned short*)p; p += (size_t)N_EDGES * 2;
    int*            bsum   = (int*)p;            p += 256 * 4;
    float*          dinv   = (float*)p;          p += (size_t)N_NODES * 4;
    __half*         w1t    = (__half*)p;         p += (size_t)IN_DIM * HID_DIM * 2;
    __half*         g1     = (__half*)p;         p += (size_t)N_NODES * HID_DIM * 2;
    __half*         g2     = (__half*)p;         p += (size_t)N_NODES * OUT_DIM * 2;

    const int NBLK = (N_NODES + 255) / 256;  // 196

    k_init<<<NBLK, 256, 0, stream>>>(cnt, W1, w1t);
    k_count<<<(N_EDGES + 255) / 256, 256, 0, stream>>>(dstp, cnt, rank_, N_EDGES);
    k_scan1<<<NBLK, 256, 0, stream>>>(cnt, rowptr, bsum);
    k_scan2<<<1, 256, 0, stream>>>(bsum, NBLK);
    k_scan3_dinv<<<NBLK, 256, 0, stream>>>(rowptr, bsum, cnt, dinv);
    k_fill<<<(N_EDGES + 255) / 256, 256, 0, stream>>>(srcp, dstp, rowptr, rank_, esrc, N_EDGES);

    k_gemm1<<<(N_NODES + 63) / 64, 256, 0, stream>>>(x, w1t, dinv, g1);

    k_agg1<<<N_NODES / 4, 256, 0, stream>>>(rowptr, esrc, dinv,
                                            (const uint2*)g1, b1, W2, g2);

    k_agg_lsm<<<(N_NODES + 3) / 4, 256, 0, stream>>>(rowptr, esrc, dinv,
                                                     (const uint2*)g2, b2, out);
}

// Round 10
// 160.324 us; speedup vs baseline: 1.1521x; 1.1521x over previous
//
#include <hip/hip_runtime.h>
#include <hip/hip_bf16.h>
#include <hip/hip_fp16.h>
#include <cstddef>

#define N_NODES 50000
#define IN_DIM 256
#define HID_DIM 64
#define OUT_DIM 40
#define N_EDGES 800000

typedef _Float16 f16x8 __attribute__((ext_vector_type(8)));
typedef float f32x4 __attribute__((ext_vector_type(4)));

// ---------------------------------------------------------------------------
// K0: zero histogram + build W1^T in fp16 (w1t[c][k] = W1[k][c])
__global__ void k_init(int* __restrict__ cnt, const float* __restrict__ W1,
                       __half* __restrict__ w1t) {
    int i = blockIdx.x * 256 + threadIdx.x;
    if (i < N_NODES) cnt[i] = 0;
    if (i < IN_DIM * HID_DIM) {
        int c = i >> 8, k = i & 255;
        w1t[i] = __float2half(W1[(size_t)k * HID_DIM + c]);
    }
}

// K1: degree histogram over dst; atomic return value = rank within dst bucket
__global__ void k_count(const int* __restrict__ dst, int* __restrict__ cnt,
                        unsigned short* __restrict__ rank_, int E) {
    int i = blockIdx.x * blockDim.x + threadIdx.x;
    if (i < E) rank_[i] = (unsigned short)atomicAdd(&cnt[dst[i]], 1);
}

// K2a: per-block exclusive scan of cnt -> rowptr (block-local) + block sums
__global__ void k_scan1(const int* __restrict__ cnt, int* __restrict__ excl,
                        int* __restrict__ bsum) {
    __shared__ int wsum[4];
    int i = blockIdx.x * 256 + threadIdx.x;
    int lane = threadIdx.x & 63, w = threadIdx.x >> 6;
    int v = (i < N_NODES) ? cnt[i] : 0;
    int inc = v;
    for (int o = 1; o < 64; o <<= 1) {
        int t = __shfl_up(inc, o);
        if (lane >= o) inc += t;
    }
    if (lane == 63) wsum[w] = inc;
    __syncthreads();
    int off = 0;
    for (int k = 0; k < w; ++k) off += wsum[k];
    if (i < N_NODES) excl[i] = off + inc - v;
    if (threadIdx.x == 255) bsum[blockIdx.x] = off + inc;
}

// K2b: single-block exclusive scan of the block sums (nb <= 256)
__global__ void k_scan2(int* __restrict__ bsum, int nb) {
    __shared__ int wsum[4];
    int i = threadIdx.x;
    int lane = i & 63, w = i >> 6;
    int v = (i < nb) ? bsum[i] : 0;
    int inc = v;
    for (int o = 1; o < 64; o <<= 1) {
        int t = __shfl_up(inc, o);
        if (lane >= o) inc += t;
    }
    if (lane == 63) wsum[w] = inc;
    __syncthreads();
    int off = 0;
    for (int k = 0; k < w; ++k) off += wsum[k];
    if (i < nb) bsum[i] = off + inc - v;
}

// K2c: add block offsets; append rowptr[N] = E; also dinv = rsqrt(deg+1)
__global__ void k_scan3_dinv(int* __restrict__ rowptr, const int* __restrict__ bsum,
                             const int* __restrict__ cnt, float* __restrict__ dinv) {
    int i = blockIdx.x * 256 + threadIdx.x;
    if (i < N_NODES) {
        rowptr[i] += bsum[blockIdx.x];
        dinv[i] = rsqrtf((float)cnt[i] + 1.0f);
    } else if (i == N_NODES) {
        rowptr[i] = N_EDGES;
    }
}

// K3: atomic-free bucket fill using precomputed rank (uint16 edge ids)
__global__ void k_fill(const int* __restrict__ src, const int* __restrict__ dst,
                       const int* __restrict__ rowptr,
                       const unsigned short* __restrict__ rank_,
                       unsigned short* __restrict__ esrc, int E) {
    int i = blockIdx.x * blockDim.x + threadIdx.x;
    if (i < E) {
        int d = dst[i];
        esrc[rowptr[d] + rank_[i]] = (unsigned short)src[i];
    }
}

// K4: g1 = dinv * (x @ W1) via fp16 MFMA (fp32 accumulate), fp16 output.
__global__ __launch_bounds__(256) void k_gemm1(const float* __restrict__ x,
        const __half* __restrict__ w1t, const float* __restrict__ dinv,
        __half* __restrict__ g1) {
    __shared__ _Float16 xh[64][264];
    __shared__ _Float16 wt[64][264];
    const int tid = threadIdx.x;
    const int row0 = blockIdx.x * 64;
    {
        int r = tid >> 2, q = tid & 3;
        const uint4* wsrc = (const uint4*)(w1t + (size_t)r * 256 + q * 64);
        uint4* wdst = (uint4*)&wt[r][q * 64];
#pragma unroll
        for (int i = 0; i < 8; ++i) wdst[i] = wsrc[i];
        int grow = row0 + r;
        const float4* xsrc = (const float4*)(x + (size_t)grow * IN_DIM + q * 64);
#pragma unroll
        for (int i = 0; i < 8; ++i) {
            float4 f0 = make_float4(0.f, 0.f, 0.f, 0.f), f1 = f0;
            if (grow < N_NODES) { f0 = xsrc[2 * i]; f1 = xsrc[2 * i + 1]; }
            f16x8 v;
            v[0] = (_Float16)f0.x; v[1] = (_Float16)f0.y;
            v[2] = (_Float16)f0.z; v[3] = (_Float16)f0.w;
            v[4] = (_Float16)f1.x; v[5] = (_Float16)f1.y;
            v[6] = (_Float16)f1.z; v[7] = (_Float16)f1.w;
            *(f16x8*)&xh[r][q * 64 + i * 8] = v;
        }
    }
    __syncthreads();
    const int wv = tid >> 6, l = tid & 63;
    const int rowa = wv * 16 + (l & 15);
    const int koff = (l >> 4) * 8;
    f32x4 acc0 = {0.f, 0.f, 0.f, 0.f}, acc1 = acc0, acc2 = acc0, acc3 = acc0;
#pragma unroll
    for (int ks = 0; ks < 8; ++ks) {
        f16x8 a  = *(const f16x8*)&xh[rowa][ks * 32 + koff];
        f16x8 b0 = *(const f16x8*)&wt[ 0 + (l & 15)][ks * 32 + koff];
        f16x8 b1 = *(const f16x8*)&wt[16 + (l & 15)][ks * 32 + koff];
        f16x8 b2 = *(const f16x8*)&wt[32 + (l & 15)][ks * 32 + koff];
        f16x8 b3 = *(const f16x8*)&wt[48 + (l & 15)][ks * 32 + koff];
        acc0 = __builtin_amdgcn_mfma_f32_16x16x32_f16(a, b0, acc0, 0, 0, 0);
        acc1 = __builtin_amdgcn_mfma_f32_16x16x32_f16(a, b1, acc1, 0, 0, 0);
        acc2 = __builtin_amdgcn_mfma_f32_16x16x32_f16(a, b2, acc2, 0, 0, 0);
        acc3 = __builtin_amdgcn_mfma_f32_16x16x32_f16(a, b3, acc3, 0, 0, 0);
    }
    // C/D: col = lane&15, row = (lane>>4)*4 + reg  [m89-verified]
    const int colc = l & 15;
#pragma unroll
    for (int r = 0; r < 4; ++r) {
        int grow = row0 + wv * 16 + (l >> 4) * 4 + r;
        if (grow < N_NODES) {
            float dv = dinv[grow];
            __half* dst = g1 + (size_t)grow * HID_DIM;
            dst[ 0 + colc] = __float2half(acc0[r] * dv);
            dst[16 + colc] = __float2half(acc1[r] * dv);
            dst[32 + colc] = __float2half(acc2[r] * dv);
            dst[48 + colc] = __float2half(acc3[r] * dv);
        }
    }
}

// K5: gather aggregation DIM=64 (pre-scaled fp16 in, fp32 out), fused bias+ReLU.
// One wave per node. Cooperative edge-id load (one coalesced ushort load per
// 64 edges) + WAVE-UNIFORM shuffles: the inner loop bound nb is identical on
// all 64 lanes, every __shfl executes with full EXEC; only gathers are
// predicated (no cross-lane ops under divergence -- fixes R9's UB).
__global__ __launch_bounds__(256) void k_agg_relu(const int* __restrict__ rowptr,
        const unsigned short* __restrict__ esrc, const float* __restrict__ dinv,
        const uint2* __restrict__ g,        // [N][16] uint2 (=64 half)
        const float* __restrict__ b,
        float* __restrict__ out) {
    int wid  = (int)((blockIdx.x * (size_t)blockDim.x + threadIdx.x) >> 6);
    int lane = threadIdx.x & 63;
    if (wid >= N_NODES) return;
    int p = lane >> 4;        // edge parity 0..3
    int c = lane & 15;        // uint2 channel group
    float ax = 0.f, ay = 0.f, az = 0.f, aw = 0.f;
#define ACC_U2(v)  do {                                            \
        float2 f0 = __half22float2(*(const __half2*)&(v).x);       \
        float2 f1 = __half22float2(*(const __half2*)&(v).y);       \
        ax += f0.x; ay += f0.y; az += f1.x; aw += f1.y; } while (0)
    if (p == 0) { uint2 v = g[(size_t)wid * 16 + c]; ACC_U2(v); }  // self-loop
    int beg = rowptr[wid], deg = rowptr[wid + 1] - beg;
    for (int base = 0; base < deg; base += 64) {          // uniform
        int nb = deg - base; if (nb > 64) nb = 64;        // uniform
        int idx = (lane < nb) ? (int)esrc[beg + base + lane] : 0;  // coalesced
        for (int eb = 0; eb < nb; eb += 16) {             // uniform bound
            int e0 = eb + p;                              // e0+12 <= 63 always
            int s0 = __shfl(idx, e0);
            int s1 = __shfl(idx, e0 + 4);
            int s2 = __shfl(idx, e0 + 8);
            int s3 = __shfl(idx, e0 + 12);
            if (e0 + 12 < nb) {                           // fast path: all 4
                uint2 v0 = g[(size_t)s0 * 16 + c];
                uint2 v1 = g[(size_t)s1 * 16 + c];
                uint2 v2 = g[(size_t)s2 * 16 + c];
                uint2 v3 = g[(size_t)s3 * 16 + c];
                ACC_U2(v0); ACC_U2(v1); ACC_U2(v2); ACC_U2(v3);
            } else {                                      // tail: per-edge guard
                if (e0      < nb) { uint2 v = g[(size_t)s0 * 16 + c]; ACC_U2(v); }
                if (e0 + 4  < nb) { uint2 v = g[(size_t)s1 * 16 + c]; ACC_U2(v); }
                if (e0 + 8  < nb) { uint2 v = g[(size_t)s2 * 16 + c]; ACC_U2(v); }
            }
        }
    }
#undef ACC_U2
    ax += __shfl_xor(ax, 16); ax += __shfl_xor(ax, 32);
    ay += __shfl_xor(ay, 16); ay += __shfl_xor(ay, 32);
    az += __shfl_xor(az, 16); az += __shfl_xor(az, 32);
    aw += __shfl_xor(aw, 16); aw += __shfl_xor(aw, 32);
    if (lane < 16) {
        float dd = dinv[wid];
        float4 bb = *(const float4*)&b[c * 4];
        float4 o;
        o.x = fmaxf(ax * dd + bb.x, 0.f);
        o.y = fmaxf(ay * dd + bb.y, 0.f);
        o.z = fmaxf(az * dd + bb.z, 0.f);
        o.w = fmaxf(aw * dd + bb.w, 0.f);
        *(float4*)&out[(size_t)wid * HID_DIM + c * 4] = o;
    }
}

// K6: g2 = dinv * (a @ W2)  [50000,64]x[64,40], pre-scaled fp16 output
__global__ void k_gemm2(const float* __restrict__ a, const float* __restrict__ W2,
                        const float* __restrict__ dinv, __half* __restrict__ g2) {
    int idx = blockIdx.x * blockDim.x + threadIdx.x;
    if (idx >= N_NODES * (OUT_DIM / 4)) return;
    int row = idx / (OUT_DIM / 4);
    int cg  = idx - row * (OUT_DIM / 4);
    const float* ar = a + (size_t)row * HID_DIM;
    float4 acc = make_float4(0.f, 0.f, 0.f, 0.f);
#pragma unroll
    for (int k = 0; k < HID_DIM; ++k) {
        float ak = ar[k];
        float4 w = *(const float4*)&W2[k * OUT_DIM + cg * 4];
        acc.x += ak * w.x; acc.y += ak * w.y; acc.z += ak * w.z; acc.w += ak * w.w;
    }
    float dv = dinv[row];
    union { __half2 h2v[2]; uint2 u; } pk;
    pk.h2v[0] = __floats2half2_rn(acc.x * dv, acc.y * dv);
    pk.h2v[1] = __floats2half2_rn(acc.z * dv, acc.w * dv);
    *(uint2*)&g2[(size_t)row * OUT_DIM + cg * 4] = pk.u;
}

// K7: layer-2 aggregation (pre-scaled fp16 in), fused bias + log_softmax.
// Same wave-uniform cooperative structure as K5.
__global__ __launch_bounds__(256) void k_agg_lsm(const int* __restrict__ rowptr,
        const unsigned short* __restrict__ esrc, const float* __restrict__ dinv,
        const uint2* __restrict__ g,        // [N][10] uint2 (=40 half)
        const float* __restrict__ b,
        float* __restrict__ out) {
    int wid  = (int)((blockIdx.x * (size_t)blockDim.x + threadIdx.x) >> 6);
    int lane = threadIdx.x & 63;
    if (wid >= N_NODES) return;
    int p = lane >> 4;
    int c = lane & 15;
    bool act = (c < 10);
    float ax = 0.f, ay = 0.f, az = 0.f, aw = 0.f;
#define ACC_U2(v)  do {                                            \
        float2 f0 = __half22float2(*(const __half2*)&(v).x);       \
        float2 f1 = __half22float2(*(const __half2*)&(v).y);       \
        ax += f0.x; ay += f0.y; az += f1.x; aw += f1.y; } while (0)
    if (p == 0 && act) { uint2 v = g[(size_t)wid * 10 + c]; ACC_U2(v); }
    int beg = rowptr[wid], deg = rowptr[wid + 1] - beg;
    for (int base = 0; base < deg; base += 64) {          // uniform
        int nb = deg - base; if (nb > 64) nb = 64;        // uniform
        int idx = (lane < nb) ? (int)esrc[beg + base + lane] : 0;
        for (int eb = 0; eb < nb; eb += 16) {             // uniform bound
            int e0 = eb + p;
            int s0 = __shfl(idx, e0);
            int s1 = __shfl(idx, e0 + 4);
            int s2 = __shfl(idx, e0 + 8);
            int s3 = __shfl(idx, e0 + 12);
            if (act) {
                if (e0 + 12 < nb) {
                    uint2 v0 = g[(size_t)s0 * 10 + c];
                    uint2 v1 = g[(size_t)s1 * 10 + c];
                    uint2 v2 = g[(size_t)s2 * 10 + c];
                    uint2 v3 = g[(size_t)s3 * 10 + c];
                    ACC_U2(v0); ACC_U2(v1); ACC_U2(v2); ACC_U2(v3);
                } else {
                    if (e0      < nb) { uint2 v = g[(size_t)s0 * 10 + c]; ACC_U2(v); }
                    if (e0 + 4  < nb) { uint2 v = g[(size_t)s1 * 10 + c]; ACC_U2(v); }
                    if (e0 + 8  < nb) { uint2 v = g[(size_t)s2 * 10 + c]; ACC_U2(v); }
                }
            }
        }
    }
#undef ACC_U2
    ax += __shfl_xor(ax, 16); ax += __shfl_xor(ax, 32);
    ay += __shfl_xor(ay, 16); ay += __shfl_xor(ay, 32);
    az += __shfl_xor(az, 16); az += __shfl_xor(az, 32);
    aw += __shfl_xor(aw, 16); aw += __shfl_xor(aw, 32);
    float dd = dinv[wid];
    float vx = -INFINITY, vy = -INFINITY, vz = -INFINITY, vw = -INFINITY;
    if (act) {
        float4 bb = *(const float4*)&b[c * 4];
        vx = ax * dd + bb.x; vy = ay * dd + bb.y;
        vz = az * dd + bb.z; vw = aw * dd + bb.w;
    }
    float m = fmaxf(fmaxf(vx, vy), fmaxf(vz, vw));
    for (int o = 8; o; o >>= 1) m = fmaxf(m, __shfl_xor(m, o));
    float es = act ? (__expf(vx - m) + __expf(vy - m) + __expf(vz - m) + __expf(vw - m)) : 0.f;
    for (int o = 8; o; o >>= 1) es += __shfl_xor(es, o);
    float ls = __logf(es);
    if (lane < 16 && act) {
        float4 o4 = make_float4(vx - m - ls, vy - m - ls, vz - m - ls, vw - m - ls);
        *(float4*)&out[(size_t)wid * OUT_DIM + c * 4] = o4;
    }
}

extern "C" void kernel_launch(void* const* d_in, const int* in_sizes, int n_in,
                              void* d_out, int out_size, void* d_ws, size_t ws_size,
                              hipStream_t stream) {
    const float* x    = (const float*)d_in[0];
    const int*   ei   = (const int*)d_in[1];
    const int*   srcp = ei;             // edge_index[0]
    const int*   dstp = ei + N_EDGES;   // edge_index[1]
    const float* W1   = (const float*)d_in[2];
    const float* b1   = (const float*)d_in[3];
    const float* W2   = (const float*)d_in[4];
    const float* b2   = (const float*)d_in[5];
    float* out = (float*)d_out;

    // workspace layout (~27 MB)
    char* p = (char*)d_ws;
    int*            cnt    = (int*)p;            p += (size_t)N_NODES * 4;
    int*            rowptr = (int*)p;            p += (size_t)(N_NODES + 4) * 4;
    unsigned short* rank_  = (unsigned short*)p; p += (size_t)N_EDGES * 2;
    unsigned short* esrc   = (unsigned short*)p; p += (size_t)N_EDGES * 2;
    int*            bsum   = (int*)p;            p += 256 * 4;
    float*          dinv   = (float*)p;          p += (size_t)N_NODES * 4;
    __half*         w1t    = (__half*)p;         p += (size_t)IN_DIM * HID_DIM * 2;
    __half*         g1     = (__half*)p;         p += (size_t)N_NODES * HID_DIM * 2;
    float*          agg1   = (float*)p;          p += (size_t)N_NODES * HID_DIM * 4;
    __half*         g2     = (__half*)p;         p += (size_t)N_NODES * OUT_DIM * 2;

    const int NBLK = (N_NODES + 255) / 256;  // 196

    k_init<<<NBLK, 256, 0, stream>>>(cnt, W1, w1t);
    k_count<<<(N_EDGES + 255) / 256, 256, 0, stream>>>(dstp, cnt, rank_, N_EDGES);
    k_scan1<<<NBLK, 256, 0, stream>>>(cnt, rowptr, bsum);
    k_scan2<<<1, 256, 0, stream>>>(bsum, NBLK);
    k_scan3_dinv<<<NBLK, 256, 0, stream>>>(rowptr, bsum, cnt, dinv);
    k_fill<<<(N_EDGES + 255) / 256, 256, 0, stream>>>(srcp, dstp, rowptr, rank_, esrc, N_EDGES);

    k_gemm1<<<(N_NODES + 63) / 64, 256, 0, stream>>>(x, w1t, dinv, g1);

    k_agg_relu<<<(N_NODES + 3) / 4, 256, 0, stream>>>(rowptr, esrc, dinv,
                                                      (const uint2*)g1, b1, agg1);

    k_gemm2<<<(N_NODES * (OUT_DIM / 4) + 255) / 256, 256, 0, stream>>>(agg1, W2, dinv, g2);

    k_agg_lsm<<<(N_NODES + 3) / 4, 256, 0, stream>>>(rowptr, esrc, dinv,
                                                     (const uint2*)g2, b2, out);
}